// Round 2
// baseline (769.657 us; speedup 1.0000x reference)
//
#include <hip/hip_runtime.h>

// LSTM fused kernel for MI355X.
// Mapping: lane = gate row (weights VGPR-resident), batch input broadcast.
// Block = 256 thr = 2 groups x 2 waves; group(2 waves, rows 0-63|64-127) owns 4
// batches; 8 batches/block -> 512 blocks (2/CU). h/c recurrence block-local.

#define FULL_UNROLL _Pragma("unroll")

__device__ __forceinline__ float sigm(float v) {
    return 1.0f / (1.0f + __expf(-v));
}
__device__ __forceinline__ float tanh_fast(float v) {
    // 1 - 2/(e^{2v}+1); graceful at +/-inf (no NaN: exp->inf => 1, exp->0 => -1)
    float e = __expf(2.0f * v);
    return 1.0f - 2.0f / (e + 1.0f);
}

__global__ __launch_bounds__(256, 2) void lstm_fused(
    const float* __restrict__ x,      // [4096][50][64]
    const float* __restrict__ W_ih,   // [128][64]
    const float* __restrict__ W_hh,   // [128][32]
    const float* __restrict__ b_ih,   // [128]
    const float* __restrict__ b_hh,   // [128]
    const float* __restrict__ W_fc,   // [64][32]
    const float* __restrict__ b_fc,   // [64]
    const int*   __restrict__ steps_p,
    float*       __restrict__ out)    // [4096][S][64]
{
    const int tid  = threadIdx.x;
    const int lane = tid & 63;
    const int wid  = tid >> 6;   // 0..3
    const int grp  = wid >> 1;   // 0..1  (group within block)
    const int wig  = wid & 1;    // wave within group: 0 -> rows 0-63, 1 -> rows 64-127
    const int S    = steps_p[0]; // 24
    const int T_TOT = 50 + S - 1;

    const int  lb0 = grp * 4;                        // group's first local batch
    const long gb0 = (long)blockIdx.x * 8 + lb0;     // global batch base of group

    __shared__ __align__(16) float h_lds[8][32];     // current hidden state
    __shared__ __align__(16) float g_lds[8][128];    // gate pre-activations
    __shared__ __align__(16) float o_lds[8][64];     // fed-back softmax output

    const int row = wig * 64 + lane;                 // this lane's gate row 0..127

    // ---- resident weights (per-lane VGPRs) ----
    float wih[64];
    {
        const float4* p = (const float4*)(W_ih + row * 64);
        FULL_UNROLL
        for (int q = 0; q < 16; ++q) {
            float4 v = p[q];
            wih[4*q+0]=v.x; wih[4*q+1]=v.y; wih[4*q+2]=v.z; wih[4*q+3]=v.w;
        }
    }
    float whh[32];
    {
        const float4* p = (const float4*)(W_hh + row * 32);
        FULL_UNROLL
        for (int q = 0; q < 8; ++q) {
            float4 v = p[q];
            whh[4*q+0]=v.x; whh[4*q+1]=v.y; whh[4*q+2]=v.z; whh[4*q+3]=v.w;
        }
    }
    const float bias = b_ih[row] + b_hh[row];
    float wfc[32];   // lane = output unit for the head
    {
        const float4* p = (const float4*)(W_fc + lane * 32);
        FULL_UNROLL
        for (int q = 0; q < 8; ++q) {
            float4 v = p[q];
            wfc[4*q+0]=v.x; wfc[4*q+1]=v.y; wfc[4*q+2]=v.z; wfc[4*q+3]=v.w;
        }
    }
    const float bfc = b_fc[lane];

    // ---- state: lane updates (j = lane&31) of local batch lb_upd ----
    const int j      = lane & 31;
    const int bu     = lane >> 5;
    const int lb_upd = lb0 + wig * 2 + bu;   // each wave owns 2 batches for update
    float c_reg = 0.0f;

    ((float*)h_lds)[tid] = 0.0f;             // 256 threads zero 8*32 floats
    __syncthreads();

    int out_step = 0;
    for (int t = 0; t < T_TOT; ++t) {
        const bool ar = (t >= 50);

        // ---------- phase A: gates for the group's 4 batches ----------
        #pragma unroll 1
        for (int bb = 0; bb < 4; ++bb) {
            const int lb = lb0 + bb;
            float a0 = bias, a1 = 0.f, a2 = 0.f, a3 = 0.f;
            // wave-uniform input vector: x (warmup) or fed-back softmax (AR)
            const float4* ip = ar ? (const float4*)(&o_lds[lb][0])
                                  : (const float4*)(x + ((gb0 + bb) * 50 + t) * 64);
            FULL_UNROLL
            for (int q = 0; q < 16; ++q) {
                float4 v = ip[q];
                a0 = fmaf(v.x, wih[4*q+0], a0);
                a1 = fmaf(v.y, wih[4*q+1], a1);
                a2 = fmaf(v.z, wih[4*q+2], a2);
                a3 = fmaf(v.w, wih[4*q+3], a3);
            }
            const float4* hp = (const float4*)(&h_lds[lb][0]);  // LDS broadcast
            FULL_UNROLL
            for (int q = 0; q < 8; ++q) {
                float4 v = hp[q];
                a0 = fmaf(v.x, whh[4*q+0], a0);
                a1 = fmaf(v.y, whh[4*q+1], a1);
                a2 = fmaf(v.z, whh[4*q+2], a2);
                a3 = fmaf(v.w, whh[4*q+3], a3);
            }
            g_lds[lb][row] = (a0 + a1) + (a2 + a3);
        }
        __syncthreads();

        // ---------- phase B: cell update (wave's 2 batches on 64 lanes) ----------
        {
            const float gi = g_lds[lb_upd][j];
            const float gf = g_lds[lb_upd][32 + j];
            const float gg = g_lds[lb_upd][64 + j];
            const float go = g_lds[lb_upd][96 + j];
            c_reg = sigm(gf) * c_reg + sigm(gi) * tanh_fast(gg);
            h_lds[lb_upd][j] = sigm(go) * tanh_fast(c_reg);
        }

        // ---------- head: last warmup step + every AR step ----------
        if (t >= 49) {
            #pragma unroll 1
            for (int pb = 0; pb < 2; ++pb) {
                const int lb = lb0 + wig * 2 + pb;   // this wave's own batches only
                float acc0 = bfc, acc1 = 0.f;
                const float4* hp = (const float4*)(&h_lds[lb][0]); // same-wave write->read
                FULL_UNROLL
                for (int q = 0; q < 8; ++q) {
                    float4 v = hp[q];
                    acc0 = fmaf(v.x, wfc[4*q+0], acc0);
                    acc1 = fmaf(v.y, wfc[4*q+1], acc1);
                    acc0 = fmaf(v.z, wfc[4*q+2], acc0);
                    acc1 = fmaf(v.w, wfc[4*q+3], acc1);
                }
                float a = fmaxf(acc0 + acc1, 0.0f);          // relu
                float m = a;                                  // 64-lane softmax
                FULL_UNROLL
                for (int d = 32; d > 0; d >>= 1) m = fmaxf(m, __shfl_xor(m, d));
                float e = __expf(a - m);
                float s = e;
                FULL_UNROLL
                for (int d = 32; d > 0; d >>= 1) s += __shfl_xor(s, d);
                float o = e / s;
                o_lds[lb][lane] = o;
                out[((gb0 + wig * 2 + pb) * S + out_step) * 64 + lane] = o;
            }
            out_step++;
        }
        __syncthreads();
    }
}

extern "C" void kernel_launch(void* const* d_in, const int* in_sizes, int n_in,
                              void* d_out, int out_size, void* d_ws, size_t ws_size,
                              hipStream_t stream) {
    const float* x    = (const float*)d_in[0];
    const float* W_ih = (const float*)d_in[1];
    const float* W_hh = (const float*)d_in[2];
    const float* b_ih = (const float*)d_in[3];
    const float* b_hh = (const float*)d_in[4];
    const float* W_fc = (const float*)d_in[5];
    const float* b_fc = (const float*)d_in[6];
    const int*   stp  = (const int*)d_in[7];
    float* out = (float*)d_out;
    (void)in_sizes; (void)n_in; (void)out_size; (void)d_ws; (void)ws_size;

    hipLaunchKernelGGL(lstm_fused, dim3(512), dim3(256), 0, stream,
                       x, W_ih, W_hh, b_ih, b_hh, W_fc, b_fc, stp, out);
}

// Round 3
// 333.679 us; speedup vs baseline: 2.3066x; 2.3066x over previous
//
#include <hip/hip_runtime.h>

// LSTM fused, round 3.
// 2048 blocks x 128 threads (2 waves). Block owns 2 batches; wave w owns gate
// rows [w*64, w*64+64) for BOTH batches, and owns batch w's cell state + head.
// Weights W_ih/W_hh VGPR-resident (96 regs); W_fc transposed in LDS.
// x double-buffered in LDS via coalesced prefetch. Warmup and AR loops split
// so no flat (generic) loads are ever generated. 2 barriers per timestep.

#define FULL_UNROLL _Pragma("unroll")

__device__ __forceinline__ float sigm(float v) {
    return 1.0f / (1.0f + __expf(-v));
}
__device__ __forceinline__ float tanh_fast(float v) {
    float e = __expf(2.0f * v);          // no NaN at +/-inf
    return 1.0f - 2.0f / (e + 1.0f);
}

__global__ __launch_bounds__(128, 4) void lstm_fused(
    const float* __restrict__ x,      // [4096][50][64]
    const float* __restrict__ W_ih,   // [128][64]
    const float* __restrict__ W_hh,   // [128][32]
    const float* __restrict__ b_ih,   // [128]
    const float* __restrict__ b_hh,   // [128]
    const float* __restrict__ W_fc,   // [64][32]
    const float* __restrict__ b_fc,   // [64]
    const int*   __restrict__ steps_p,
    float*       __restrict__ out)    // [4096][S][64]
{
    const int tid  = threadIdx.x;
    const int lane = tid & 63;
    const int w    = tid >> 6;                 // wave 0/1
    const int S    = steps_p[0];               // 24
    const long gb  = (long)blockIdx.x * 2;     // block's first batch

    __shared__ __align__(16) float xs[2][2][64];    // double-buffered x_t
    __shared__ __align__(16) float h_lds[2][32];
    __shared__ __align__(16) float g_lds[2][128];
    __shared__ __align__(16) float o_lds[2][64];
    __shared__ __align__(16) float wfct[32][64];    // W_fc transposed [j][o]

    const int row = (w << 6) | lane;           // this lane's gate row 0..127

    // ---- resident weights ----
    float wih[64];
    {
        const float4* p = (const float4*)(W_ih + row * 64);
        FULL_UNROLL
        for (int q = 0; q < 16; ++q) {
            float4 v = p[q];
            wih[4*q+0]=v.x; wih[4*q+1]=v.y; wih[4*q+2]=v.z; wih[4*q+3]=v.w;
        }
    }
    float whh[32];
    {
        const float4* p = (const float4*)(W_hh + row * 32);
        FULL_UNROLL
        for (int q = 0; q < 8; ++q) {
            float4 v = p[q];
            whh[4*q+0]=v.x; whh[4*q+1]=v.y; whh[4*q+2]=v.z; whh[4*q+3]=v.w;
        }
    }
    const float bias = b_ih[row] + b_hh[row];
    const float bfc  = b_fc[lane];

    // ---- W_fc -> LDS transposed (2048 floats, 16 per thread, coalesced) ----
    FULL_UNROLL
    for (int k = 0; k < 16; ++k) {
        int idx = tid + (k << 7);              // 0..2047
        wfct[idx & 31][idx >> 5] = W_fc[idx];
    }

    // ---- init state, stage x[t=0] ----
    if (tid < 64) ((float*)h_lds)[tid] = 0.0f;
    xs[0][w][lane] = x[(gb + w) * 3200 + lane];
    float c_reg = 0.0f;
    __syncthreads();

    // ================= warmup: t = 0..48 =================
    #pragma unroll 1
    for (int t = 0; t < 49; ++t) {
        // prefetch x[t+1] (coalesced 1 float/thread); latency hides under FMAs
        const float xr = x[(gb + w) * 3200 + (t + 1) * 64 + lane];

        // phase A: gates for both batches from LDS-broadcast x & h
        #pragma unroll 1
        for (int b = 0; b < 2; ++b) {
            float a0 = bias, a1 = 0.f, a2 = 0.f, a3 = 0.f;
            const float4* ip = (const float4*)&xs[t & 1][b][0];
            FULL_UNROLL
            for (int q = 0; q < 16; ++q) {
                float4 v = ip[q];
                a0 = fmaf(v.x, wih[4*q+0], a0);
                a1 = fmaf(v.y, wih[4*q+1], a1);
                a2 = fmaf(v.z, wih[4*q+2], a2);
                a3 = fmaf(v.w, wih[4*q+3], a3);
            }
            const float4* hp = (const float4*)&h_lds[b][0];
            FULL_UNROLL
            for (int q = 0; q < 8; ++q) {
                float4 v = hp[q];
                a0 = fmaf(v.x, whh[4*q+0], a0);
                a1 = fmaf(v.y, whh[4*q+1], a1);
                a2 = fmaf(v.z, whh[4*q+2], a2);
                a3 = fmaf(v.w, whh[4*q+3], a3);
            }
            g_lds[b][row] = (a0 + a1) + (a2 + a3);
        }
        xs[(t + 1) & 1][w][lane] = xr;         // publish staged x
        __syncthreads();

        // phase B: wave w updates batch w (lanes 0..31)
        if (lane < 32) {
            const int j = lane;
            const float gi = g_lds[w][j];
            const float gf = g_lds[w][32 + j];
            const float gg = g_lds[w][64 + j];
            const float go = g_lds[w][96 + j];
            c_reg = sigm(gf) * c_reg + sigm(gi) * tanh_fast(gg);
            h_lds[w][j] = sigm(go) * tanh_fast(c_reg);
        }
        __syncthreads();
    }

    // ================= AR: t = 49 .. 49+S-1 (head every step) =================
    #pragma unroll 1
    for (int s = 0; s < S; ++s) {
        // input: final staged x for s==0 (parity 49&1==1), else fed-back softmax
        const float (*inp)[64] = (s == 0) ? xs[1] : o_lds;   // both LDS

        #pragma unroll 1
        for (int b = 0; b < 2; ++b) {
            float a0 = bias, a1 = 0.f, a2 = 0.f, a3 = 0.f;
            const float4* ip = (const float4*)&inp[b][0];
            FULL_UNROLL
            for (int q = 0; q < 16; ++q) {
                float4 v = ip[q];
                a0 = fmaf(v.x, wih[4*q+0], a0);
                a1 = fmaf(v.y, wih[4*q+1], a1);
                a2 = fmaf(v.z, wih[4*q+2], a2);
                a3 = fmaf(v.w, wih[4*q+3], a3);
            }
            const float4* hp = (const float4*)&h_lds[b][0];
            FULL_UNROLL
            for (int q = 0; q < 8; ++q) {
                float4 v = hp[q];
                a0 = fmaf(v.x, whh[4*q+0], a0);
                a1 = fmaf(v.y, whh[4*q+1], a1);
                a2 = fmaf(v.z, whh[4*q+2], a2);
                a3 = fmaf(v.w, whh[4*q+3], a3);
            }
            g_lds[b][row] = (a0 + a1) + (a2 + a3);
        }
        __syncthreads();

        // cell update: wave w, batch w, lanes 0..31
        if (lane < 32) {
            const int j = lane;
            const float gi = g_lds[w][j];
            const float gf = g_lds[w][32 + j];
            const float gg = g_lds[w][64 + j];
            const float go = g_lds[w][96 + j];
            c_reg = sigm(gf) * c_reg + sigm(gi) * tanh_fast(gg);
            h_lds[w][j] = sigm(go) * tanh_fast(c_reg);
        }

        // head: wave w on batch w (same-wave h readback, no extra barrier)
        {
            float acc = bfc;
            const float4* hp = (const float4*)&h_lds[w][0];
            FULL_UNROLL
            for (int q = 0; q < 8; ++q) {
                float4 hv = hp[q];
                acc = fmaf(hv.x, wfct[4*q+0][lane], acc);
                acc = fmaf(hv.y, wfct[4*q+1][lane], acc);
                acc = fmaf(hv.z, wfct[4*q+2][lane], acc);
                acc = fmaf(hv.w, wfct[4*q+3][lane], acc);
            }
            float a = fmaxf(acc, 0.0f);
            float m = a;
            FULL_UNROLL
            for (int d = 32; d > 0; d >>= 1) m = fmaxf(m, __shfl_xor(m, d));
            float e = __expf(a - m);
            float sm = e;
            FULL_UNROLL
            for (int d = 32; d > 0; d >>= 1) sm += __shfl_xor(sm, d);
            float o = e / sm;
            o_lds[w][lane] = o;
            out[(gb + w) * (long)S * 64 + (long)s * 64 + lane] = o;
        }
        __syncthreads();
    }
}

extern "C" void kernel_launch(void* const* d_in, const int* in_sizes, int n_in,
                              void* d_out, int out_size, void* d_ws, size_t ws_size,
                              hipStream_t stream) {
    const float* x    = (const float*)d_in[0];
    const float* W_ih = (const float*)d_in[1];
    const float* W_hh = (const float*)d_in[2];
    const float* b_ih = (const float*)d_in[3];
    const float* b_hh = (const float*)d_in[4];
    const float* W_fc = (const float*)d_in[5];
    const float* b_fc = (const float*)d_in[6];
    const int*   stp  = (const int*)d_in[7];
    float* out = (float*)d_out;
    (void)in_sizes; (void)n_in; (void)out_size; (void)d_ws; (void)ws_size;

    hipLaunchKernelGGL(lstm_fused, dim3(2048), dim3(128), 0, stream,
                       x, W_ih, W_hh, b_ih, b_hh, W_fc, b_fc, stp, out);
}

// Round 13
// 312.748 us; speedup vs baseline: 2.4609x; 1.0669x over previous
//
#include <hip/hip_runtime.h>

// LSTM fused, round 5: wave = 1 batch, ZERO LDS, ZERO barriers.
// (round-4 design + fix: bias1 was never added to the A1 gate accumulator)
// Lane l holds gate rows (l, 64+l): wih 2x64 + whh 2x32 + wfc 32 = 224 VGPRs.
// Uniform inputs (x_t, h, fed-back o) delivered via v_readlane -> SGPR ->
// v_fmac(v, s, v). Cell gates pair via 2x shfl_xor(32):
//   lane l<32:  A0=i_l (row l),     A1=g_l (row 64+l)
//   lane l>=32: A0=f_j (row 32+j),  A1=o_j (row 96+j),  j=l-32
// Both pair-lanes update cell j redundantly -> h_{l&31} in every lane.
// Head: lane = output unit; h via SGPRs; 64-lane shuffle softmax.
// 1024 blocks x 256 thr (4 independent waves/block). 2 waves/SIMD by design.

#define FULL_UNROLL _Pragma("unroll")

__device__ __forceinline__ float rdl(float v, int srclane) {
    return __int_as_float(__builtin_amdgcn_readlane(__float_as_int(v), srclane));
}
__device__ __forceinline__ float sigm(float v) {
    return 1.0f / (1.0f + __expf(-v));
}
__device__ __forceinline__ float tanh_fast(float v) {
    float e = __expf(2.0f * v);          // no NaN at +/-inf
    return 1.0f - 2.0f / (e + 1.0f);
}

__global__ __launch_bounds__(256, 2) void lstm_wavebatch(
    const float* __restrict__ x,      // [4096][50][64]
    const float* __restrict__ W_ih,   // [128][64]
    const float* __restrict__ W_hh,   // [128][32]
    const float* __restrict__ b_ih,   // [128]
    const float* __restrict__ b_hh,   // [128]
    const float* __restrict__ W_fc,   // [64][32]
    const float* __restrict__ b_fc,   // [64]
    const int*   __restrict__ steps_p,
    float*       __restrict__ out)    // [4096][S][64]
{
    const int lane = threadIdx.x & 63;
    const int wv   = threadIdx.x >> 6;
    const long b   = (long)blockIdx.x * 4 + wv;   // wave's batch
    const int  S   = steps_p[0];                  // 24

    const int r0 = lane;        // gate row 0
    const int r1 = 64 + lane;   // gate row 1

    // ---- resident weights (per-lane VGPRs) ----
    float wih0[64], wih1[64];
    {
        const float4* p0 = (const float4*)(W_ih + r0 * 64);
        const float4* p1 = (const float4*)(W_ih + r1 * 64);
        FULL_UNROLL
        for (int q = 0; q < 16; ++q) {
            float4 v0 = p0[q], v1 = p1[q];
            wih0[4*q+0]=v0.x; wih0[4*q+1]=v0.y; wih0[4*q+2]=v0.z; wih0[4*q+3]=v0.w;
            wih1[4*q+0]=v1.x; wih1[4*q+1]=v1.y; wih1[4*q+2]=v1.z; wih1[4*q+3]=v1.w;
        }
    }
    float whh0[32], whh1[32];
    {
        const float4* p0 = (const float4*)(W_hh + r0 * 32);
        const float4* p1 = (const float4*)(W_hh + r1 * 32);
        FULL_UNROLL
        for (int q = 0; q < 8; ++q) {
            float4 v0 = p0[q], v1 = p1[q];
            whh0[4*q+0]=v0.x; whh0[4*q+1]=v0.y; whh0[4*q+2]=v0.z; whh0[4*q+3]=v0.w;
            whh1[4*q+0]=v1.x; whh1[4*q+1]=v1.y; whh1[4*q+2]=v1.z; whh1[4*q+3]=v1.w;
        }
    }
    float wfc_r[32];
    {
        const float4* p = (const float4*)(W_fc + lane * 32);
        FULL_UNROLL
        for (int q = 0; q < 8; ++q) {
            float4 v = p[q];
            wfc_r[4*q+0]=v.x; wfc_r[4*q+1]=v.y; wfc_r[4*q+2]=v.z; wfc_r[4*q+3]=v.w;
        }
    }
    const float bias0 = b_ih[r0] + b_hh[r0];
    const float bias1 = b_ih[r1] + b_hh[r1];
    const float bfc   = b_fc[lane];

    float c_reg = 0.0f;
    float h_v   = 0.0f;   // h_{lane&31}, duplicated in pair lanes
    float o_v   = 0.0f;   // fed-back softmax output, lane = unit

    const float* xb = x + b * 3200;   // this batch's x [50][64]
    float xa = xb[lane];              // x[t=0], lane = element (coalesced)

    // ================= warmup: t = 0..49 =================
    #pragma unroll 1
    for (int t = 0; t < 50; ++t) {
        const int tn = (t < 49) ? t + 1 : 49;          // safe prefetch addr
        const float xn = xb[tn * 64 + lane];           // prefetch x[t+1]

        float A0a = bias0, A0b = 0.f, A1a = bias1, A1b = 0.f;   // FIX: bias1 seeded
        // x part: 64 uniform inputs via readlane -> SGPR
        FULL_UNROLL
        for (int k = 0; k < 64; k += 2) {
            const float s0 = rdl(xa, k);
            const float s1 = rdl(xa, k + 1);
            A0a = fmaf(s0, wih0[k],   A0a);
            A1a = fmaf(s0, wih1[k],   A1a);
            A0b = fmaf(s1, wih0[k+1], A0b);
            A1b = fmaf(s1, wih1[k+1], A1b);
        }
        // h part: 32 uniform inputs
        FULL_UNROLL
        for (int j = 0; j < 32; j += 2) {
            const float s0 = rdl(h_v, j);
            const float s1 = rdl(h_v, j + 1);
            A0a = fmaf(s0, whh0[j],   A0a);
            A1a = fmaf(s0, whh1[j],   A1a);
            A0b = fmaf(s1, whh0[j+1], A0b);
            A1b = fmaf(s1, whh1[j+1], A1b);
        }
        const float A0 = A0a + A0b;
        const float A1 = A1a + A1b;

        // cell update via pair exchange
        const float B0 = __shfl_xor(A0, 32);
        const float B1 = __shfl_xor(A1, 32);
        const bool lo = (lane < 32);
        const float gi = lo ? A0 : B0;
        const float gf = lo ? B0 : A0;
        const float gg = lo ? A1 : B1;
        const float go = lo ? B1 : A1;
        c_reg = sigm(gf) * c_reg + sigm(gi) * tanh_fast(gg);
        h_v   = sigm(go) * tanh_fast(c_reg);

        xa = xn;
    }

    // ================= head + AR steps =================
    float* outb = out + b * (long)S * 64;
    #pragma unroll 1
    for (int s = 0; s < S; ++s) {
        if (s > 0) {
            // gates from fed-back o (64) + h (32)
            float A0a = bias0, A0b = 0.f, A1a = bias1, A1b = 0.f;  // FIX: bias1 seeded
            FULL_UNROLL
            for (int k = 0; k < 64; k += 2) {
                const float s0 = rdl(o_v, k);
                const float s1 = rdl(o_v, k + 1);
                A0a = fmaf(s0, wih0[k],   A0a);
                A1a = fmaf(s0, wih1[k],   A1a);
                A0b = fmaf(s1, wih0[k+1], A0b);
                A1b = fmaf(s1, wih1[k+1], A1b);
            }
            FULL_UNROLL
            for (int j = 0; j < 32; j += 2) {
                const float s0 = rdl(h_v, j);
                const float s1 = rdl(h_v, j + 1);
                A0a = fmaf(s0, whh0[j],   A0a);
                A1a = fmaf(s0, whh1[j],   A1a);
                A0b = fmaf(s1, whh0[j+1], A0b);
                A1b = fmaf(s1, whh1[j+1], A1b);
            }
            const float A0 = A0a + A0b;
            const float A1 = A1a + A1b;
            const float B0 = __shfl_xor(A0, 32);
            const float B1 = __shfl_xor(A1, 32);
            const bool lo = (lane < 32);
            const float gi = lo ? A0 : B0;
            const float gf = lo ? B0 : A0;
            const float gg = lo ? A1 : B1;
            const float go = lo ? B1 : A1;
            c_reg = sigm(gf) * c_reg + sigm(gi) * tanh_fast(gg);
            h_v   = sigm(go) * tanh_fast(c_reg);
        }

        // head: lane = output unit; h via SGPR readlanes
        float acc_a = bfc, acc_b = 0.f;
        FULL_UNROLL
        for (int j = 0; j < 32; j += 2) {
            acc_a = fmaf(rdl(h_v, j),     wfc_r[j],   acc_a);
            acc_b = fmaf(rdl(h_v, j + 1), wfc_r[j+1], acc_b);
        }
        float a = fmaxf(acc_a + acc_b, 0.0f);          // relu
        float m = a;                                    // 64-lane softmax
        FULL_UNROLL
        for (int d = 32; d > 0; d >>= 1) m = fmaxf(m, __shfl_xor(m, d));
        const float e = __expf(a - m);
        float sm = e;
        FULL_UNROLL
        for (int d = 32; d > 0; d >>= 1) sm += __shfl_xor(sm, d);
        o_v = e / sm;
        outb[(long)s * 64 + lane] = o_v;               // coalesced
    }
}

extern "C" void kernel_launch(void* const* d_in, const int* in_sizes, int n_in,
                              void* d_out, int out_size, void* d_ws, size_t ws_size,
                              hipStream_t stream) {
    const float* x    = (const float*)d_in[0];
    const float* W_ih = (const float*)d_in[1];
    const float* W_hh = (const float*)d_in[2];
    const float* b_ih = (const float*)d_in[3];
    const float* b_hh = (const float*)d_in[4];
    const float* W_fc = (const float*)d_in[5];
    const float* b_fc = (const float*)d_in[6];
    const int*   stp  = (const int*)d_in[7];
    float* out = (float*)d_out;
    (void)in_sizes; (void)n_in; (void)out_size; (void)d_ws; (void)ws_size;

    hipLaunchKernelGGL(lstm_wavebatch, dim3(1024), dim3(256), 0, stream,
                       x, W_ih, W_hh, b_ih, b_hh, W_fc, b_fc, stp, out);
}